// Round 5
// baseline (473.256 us; speedup 1.0000x reference)
//
#include <hip/hip_runtime.h>
#include <stdint.h>

#define XD 1024
#define NS 65536
#define SPB 16
#define N1 256
#define N2 64

#if __has_builtin(__builtin_amdgcn_exp2f)
#define EXP2F(x) __builtin_amdgcn_exp2f(x)
#else
#define EXP2F(x) exp2f(x)
#endif
#if __has_builtin(__builtin_amdgcn_logf)
#define LOG2F(x) __builtin_amdgcn_logf(x)
#else
#define LOG2F(x) log2f(x)
#endif
#if __has_builtin(__builtin_amdgcn_rcpf)
#define RCPF(x) __builtin_amdgcn_rcpf(x)
#else
#define RCPF(x) (1.0f/(x))
#endif

typedef __attribute__((ext_vector_type(8))) short short8;
typedef __attribute__((ext_vector_type(4))) float float4v;
typedef __attribute__((ext_vector_type(2))) float float2v;

#define LOG2E 1.4426950408889634f
#define LN2   0.6931471805599453f
#define NL2LN2 0.5287663729448977f

// pk layout (shorts): [0 .. 131071]   W3 frags (2 mats x 64 cc x 2 kh x 64 lanes x 8)
//                     [131072 .. ]    W2 B-frags (2 mats x 4 cw x 8 ks x 64 lanes x 8)
#define PK2_OFF 131072

static __device__ __forceinline__ float tanh_fast(float x){
  float e = EXP2F(x * 2.8853900817779268f);   // e^(2x)
  return (e - 1.0f) * RCPF(e + 1.0f);
}
static __device__ __forceinline__ unsigned short f2bf(float x){
  union { float f; uint32_t u; } c; c.f = x;
  uint32_t u = c.u;
  return (unsigned short)((u + 0x7FFFu + ((u >> 16) & 1u)) >> 16);
}
static __device__ __forceinline__ float2v exp2p(float2v e){
  float2v r; r.x = EXP2F(e.x); r.y = EXP2F(e.y); return r;
}
static __device__ __forceinline__ float2v v2log2(float2v a){
  float2v r; r.x = LOG2F(a.x); r.y = LOG2F(a.y); return r;
}
// softplus(y)/ln2 = log2(1 + 2^(y*LOG2E)).
// Valid without max-stabilization: |y| <= ~8.3 structurally (W3/b3 bounds).
static __device__ __forceinline__ float2v spb2u(float2v y){
  float2v a = y * LOG2E;
  float2v e; e.x = EXP2F(a.x); e.y = EXP2F(a.y);
  return v2log2(1.0f + e);
}
// 2^x for |x| <= ~1.06 via degree-5 Taylor of e^(x ln2); rel err <= ~2e-4.
// Replaces a quarter-rate v_exp with 5 packed FMAs (trans pipe is the wall).
static __device__ __forceinline__ float2v exp2poly(float2v x){
  float2v r = x * 0.00133335581f + 0.00961812911f;
  r = r * x + 0.05550410866f;
  r = r * x + 0.24022650696f;
  r = r * x + 0.69314718056f;
  r = r * x + 1.0f;
  return r;
}

// log2(j!) for j=0..19 (runtime table only needs 0..9 for data!)
#define G2TAB_INIT {0.0f,0.0f,1.0f,2.5849625007f,4.5849625007f,6.9068905956f, \
  9.4918530963f,12.2992080189f,15.2992080189f,18.4691332114f,21.7910613063f, \
  25.2504929251f,28.8354554258f,32.5358951439f,36.3432500660f,40.2501406616f, \
  44.2501406616f,48.3376035030f,52.5075285040f,56.7554560173f}

// Pack W3 [64][1024] and W2 [256][64] (fp32 row-major) into bf16 MFMA frag order.
__global__ void pack_weights(const float* __restrict__ W3r, const float* __restrict__ W3v,
                             const float* __restrict__ W2r, const float* __restrict__ W2v,
                             unsigned short* __restrict__ pk){
  int tid = blockIdx.x * 256 + threadIdx.x;   // 0..20479
  unsigned short t[8];
  if (tid < 16384){
    int mat  = tid >> 13;
    int cc   = (tid >> 7) & 63;
    int kh   = (tid >> 6) & 1;
    int l    = tid & 63;
    int col  = cc * 16 + (l & 15);
    const float* W3 = mat ? W3v : W3r;
    int kbase = kh * 32 + (l >> 4) * 8;
    #pragma unroll
    for (int j = 0; j < 8; ++j) t[j] = f2bf(W3[(size_t)(kbase + j) * XD + col]);
    uint4 val;
    val.x = (uint32_t)t[0] | ((uint32_t)t[1] << 16);
    val.y = (uint32_t)t[2] | ((uint32_t)t[3] << 16);
    val.z = (uint32_t)t[4] | ((uint32_t)t[5] << 16);
    val.w = (uint32_t)t[6] | ((uint32_t)t[7] << 16);
    *(uint4*)(pk + (size_t)tid * 8) = val;
  } else {
    int t2 = tid - 16384;                     // 0..4095
    int mat = t2 >> 11;
    int cw  = (t2 >> 9) & 3;
    int ks  = (t2 >> 6) & 7;
    int l   = t2 & 63;
    const float* W2 = mat ? W2v : W2r;
    int kbase = ks * 32 + (l >> 4) * 8;
    int col = cw * 16 + (l & 15);
    #pragma unroll
    for (int j = 0; j < 8; ++j) t[j] = f2bf(W2[(size_t)(kbase + j) * N2 + col]);
    uint4 val;
    val.x = (uint32_t)t[0] | ((uint32_t)t[1] << 16);
    val.y = (uint32_t)t[2] | ((uint32_t)t[3] << 16);
    val.z = (uint32_t)t[4] | ((uint32_t)t[5] << 16);
    val.w = (uint32_t)t[6] | ((uint32_t)t[7] << 16);
    *(uint4*)(pk + (size_t)(PK2_OFF) + (size_t)t2 * 8) = val;
  }
}

// launch_bounds(256,4): VGPR cap 128. (256,8) forced 32 VGPRs -> scratch spills
// (WRITE_SIZE 65MB) and 43% regression. Occupancy pinned at 4 waves/SIMD
// (vgpr+acc > 64 total; the 8-wave bin needs <=64 -> spills).
// NOTE: inline-asm v_pk_* helpers (round 3) produced NaN at runtime — do not
// reintroduce; plain float2v ops select v_pk_*_f32 via ISel on gfx950.
__global__ __launch_bounds__(256, 4) void cmp_fused(
    const float* __restrict__ w,   const float* __restrict__ data,
    const float* __restrict__ W1r, const float* __restrict__ b1r,
    const float* __restrict__ b2r, const float* __restrict__ b3r,
    const float* __restrict__ W1v, const float* __restrict__ b1v,
    const float* __restrict__ b2v, const float* __restrict__ b3v,
    const unsigned short* __restrict__ pk,
    float* __restrict__ out)
{
  __shared__ float wtile[SPB][32];
  __shared__ __align__(16) unsigned short h1lds[SPB * 264];   // stride 264 (pad +8)
  __shared__ __align__(16) unsigned short h2lds[2][SPB * 72]; // stride 72 (pad +8)
  __shared__ float lgf2[20];
  __shared__ float redbuf[SPB];

  const float G2tab[20] = G2TAB_INIT;

  int tid = threadIdx.x;
  int s0  = blockIdx.x * SPB;
  int lane = tid & 63;
  int wv_id = tid >> 6;
  int quad = lane >> 4;
  int mrow = lane & 15;

  if (tid < 20)  lgf2[tid] = G2tab[tid];
  if (tid < SPB) redbuf[tid] = 0.0f;
  #pragma unroll
  for (int i = 0; i < 2; ++i)
    ((float*)wtile)[tid + 256 * i] = w[(size_t)s0 * 32 + tid + 256 * i];
  __syncthreads();

  // ---------------- phase 1: MLP layers 1-2 ----------------
  const short8* B2p = (const short8*)(pk + PK2_OFF);
  for (int mat = 0; mat < 2; ++mat){
    const float* W1 = mat ? W1v : W1r;
    const float* b1 = mat ? b1v : b1r;
    const float* b2 = mat ? b2v : b2r;
    // layer1 (fp32 VALU): thread = output unit u (256), loop over 16 samples
    {
      int u = tid;
      float w1reg[16];
      #pragma unroll
      for (int k = 0; k < 16; ++k) w1reg[k] = W1[k * N1 + u];
      float bu = b1[u];
      int c0 = mat ? 2 : 0;   // rate uses w chunks {0,1,4,5}; v uses {2,3,6,7}
      for (int s = 0; s < SPB; ++s){
        const float4v* wr = (const float4v*)&wtile[s][0];
        float4v a = wr[c0], b = wr[c0 + 1], c = wr[c0 + 4], d = wr[c0 + 5];
        float acc = bu;
        acc = fmaf(a.x, w1reg[0],  acc); acc = fmaf(a.y, w1reg[1],  acc);
        acc = fmaf(a.z, w1reg[2],  acc); acc = fmaf(a.w, w1reg[3],  acc);
        acc = fmaf(b.x, w1reg[4],  acc); acc = fmaf(b.y, w1reg[5],  acc);
        acc = fmaf(b.z, w1reg[6],  acc); acc = fmaf(b.w, w1reg[7],  acc);
        acc = fmaf(c.x, w1reg[8],  acc); acc = fmaf(c.y, w1reg[9],  acc);
        acc = fmaf(c.z, w1reg[10], acc); acc = fmaf(c.w, w1reg[11], acc);
        acc = fmaf(d.x, w1reg[12], acc); acc = fmaf(d.y, w1reg[13], acc);
        acc = fmaf(d.z, w1reg[14], acc); acc = fmaf(d.w, w1reg[15], acc);
        h1lds[s * 264 + u] = f2bf(tanh_fast(acc));
      }
    }
    __syncthreads();
    // layer2 (MFMA): wave wv_id -> n-chunk cw (16 units). M=16 samples, K=256.
    {
      int cw = wv_id;
      float4v acc = {0,0,0,0};
      #pragma unroll
      for (int ks = 0; ks < 8; ++ks){
        short8 bfr = B2p[(size_t)((mat * 4 + cw) * 8 + ks) * 64 + lane];
        short8 a = *(const short8*)&h1lds[mrow * 264 + ks * 32 + quad * 8];
        acc = __builtin_amdgcn_mfma_f32_16x16x32_bf16(a, bfr, acc, 0, 0, 0);
      }
      float b2n = b2[cw * 16 + mrow];
      #pragma unroll
      for (int r = 0; r < 4; ++r){
        int sample = quad * 4 + r;
        h2lds[mat][sample * 72 + cw * 16 + mrow] = f2bf(tanh_fast(acc[r] + b2n));
      }
    }
    __syncthreads();
  }

  // ---------------- phase 2: layer3 MFMA (A=W3, B=h2) + packed elementwise ----
  // B-frag: h2[k=unit][n=sample]; lane holds n=mrow (one sample), k=quad*8+j
  short8 bh[2][2];   // [mat][k-half]
  #pragma unroll
  for (int mat = 0; mat < 2; ++mat)
    #pragma unroll
    for (int kh = 0; kh < 2; ++kh)
      bh[mat][kh] = *(const short8*)&h2lds[mat][mrow * 72 + kh * 32 + quad * 8];

  // split accumulators (plain vector ops): shorter dependency chains
  float2v accA[2] = {{0, 0}, {0, 0}};
  float2v accB[2] = {{0, 0}, {0, 0}};
  const short8* Bp = (const short8*)pk;
  const float* drow = data + (size_t)(s0 + mrow) * XD;

  // prefetch pipeline registers for iteration 0
  int cc0 = wv_id * 16;
  short8 ar0 = Bp[(size_t)(cc0 * 2 + 0) * 64 + lane];
  short8 ar1 = Bp[(size_t)(cc0 * 2 + 1) * 64 + lane];
  short8 av0 = Bp[(size_t)((64 + cc0) * 2 + 0) * 64 + lane];
  short8 av1 = Bp[(size_t)((64 + cc0) * 2 + 1) * 64 + lane];
  int colq0 = cc0 * 16 + quad * 4;
  float4v b3rv = *(const float4v*)(b3r + colq0);
  float4v b3vv = *(const float4v*)(b3v + colq0);
  float4v dv   = *(const float4v*)(drow + colq0);

  for (int it = 0; it < 16; ++it){
    // stash current, prefetch next (uniform branch)
    short8 car0 = ar0, car1 = ar1, cav0 = av0, cav1 = av1;
    float4v cb3r = b3rv, cb3v = b3vv, cdv = dv;
    if (it < 15){
      int cc = wv_id * 16 + it + 1;
      ar0 = Bp[(size_t)(cc * 2 + 0) * 64 + lane];
      ar1 = Bp[(size_t)(cc * 2 + 1) * 64 + lane];
      av0 = Bp[(size_t)((64 + cc) * 2 + 0) * 64 + lane];
      av1 = Bp[(size_t)((64 + cc) * 2 + 1) * 64 + lane];
      int colq = cc * 16 + quad * 4;
      b3rv = *(const float4v*)(b3r + colq);
      b3vv = *(const float4v*)(b3v + colq);
      dv   = *(const float4v*)(drow + colq);
    }
    float4v cr = {0,0,0,0}, cv = {0,0,0,0};
    cr = __builtin_amdgcn_mfma_f32_16x16x32_bf16(car0, bh[0][0], cr, 0, 0, 0);
    cr = __builtin_amdgcn_mfma_f32_16x16x32_bf16(car1, bh[0][1], cr, 0, 0, 0);
    cv = __builtin_amdgcn_mfma_f32_16x16x32_bf16(cav0, bh[1][0], cv, 0, 0, 0);
    cv = __builtin_amdgcn_mfma_f32_16x16x32_bf16(cav1, bh[1][1], cv, 0, 0, 0);
    // vector-typed bias adds
    float4v yr4 = cr + cb3r;
    float4v yv4 = cv + cb3v;
    // process the 4 columns as 2 packed pairs
    #pragma unroll
    for (int p = 0; p < 2; ++p){
      float2v yr = {yr4[2*p], yr4[2*p+1]};
      float2v yv = {yv4[2*p], yv4[2*p+1]};
      float2v d2 = {cdv[2*p], cdv[2*p+1]};
      // rate side: spr = softplus(yr)/ln2; L2 = log2(rate); rate via rcp
      float2v spr = spb2u(yr);
      float2v L2  = NL2LN2 - v2log2(spr);
      float2v rate;
      rate.x = RCPF(spr.x) * LOG2E;
      rate.y = RCPF(spr.y) * LOG2E;
      // v side: nv = -v = -softplus(yv)
      float2v nv = spb2u(yv) * (-LN2);
      // rq_j = rate * j^-v. Small primes from v_exp; large primes (11,13,17,19)
      // as composite * near-1 correction, correction via exp2poly (trans pipe
      // is the bottleneck: swaps 8 quarter-rate v_exp for 24 packed FMAs).
      // 11 = 12*(11/12), 13 = 12*(13/12), 17 = 16*(17/16), 19 = 18*(19/18);
      // |nv*log2(ratio)| <= 1.05 -> poly valid.
      float2v q2  = exp2p(nv);
      float2v q3  = exp2p(nv * 1.58496250f);
      float2v q5  = exp2p(nv * 2.32192809f);
      float2v q7  = exp2p(nv * 2.80735492f);
      float2v P11 = exp2poly(nv * -0.12553088f);
      float2v P13 = exp2poly(nv *  0.11547722f);
      float2v P17 = exp2poly(nv *  0.08746284f);
      float2v P19 = exp2poly(nv *  0.07800251f);
      float2v rq2  = rate * q2,  rq3  = rate * q3,  rq5 = rate * q5,  rq7 = rate * q7;
      float2v rq4  = rq2 * q2,  rq6  = rq2 * q3,  rq8 = rq4 * q2,  rq9 = rq3 * q3;
      float2v rq10 = rq5 * q2;
      float2v rq12 = rq4 * q3,  rq14 = rq2 * q7,  rq15 = rq3 * q5;
      float2v rq16 = rq8 * q2,  rq18 = rq9 * q2;
      float2v rq11 = rq12 * P11, rq13 = rq12 * P13;
      float2v rq17 = rq16 * P17, rq19 = rq18 * P19;
      // Z = 1 + rate*(1 + rq2*(1 + rq3*(... (1 + rq19) ...))): 19 packed FMAs
      float2v zi = 1.0f + rq19;
      zi = rq18 * zi + 1.0f;
      zi = rq17 * zi + 1.0f;
      zi = rq16 * zi + 1.0f;
      zi = rq15 * zi + 1.0f;
      zi = rq14 * zi + 1.0f;
      zi = rq13 * zi + 1.0f;
      zi = rq12 * zi + 1.0f;
      zi = rq11 * zi + 1.0f;
      zi = rq10 * zi + 1.0f;
      zi = rq9  * zi + 1.0f;
      zi = rq8  * zi + 1.0f;
      zi = rq7  * zi + 1.0f;
      zi = rq6  * zi + 1.0f;
      zi = rq5  * zi + 1.0f;
      zi = rq4  * zi + 1.0f;
      zi = rq3  * zi + 1.0f;
      zi = rq2  * zi + 1.0f;
      float2v Z = rate * zi + 1.0f;
      float2v lZ = v2log2(Z);
      float2v vlg; vlg.x = lgf2[(int)d2.x]; vlg.y = lgf2[(int)d2.y];
      // log2-scaled logpmf: d*L2 + nv*log2(d!) - log2Z (split across 2 accs)
      accA[p] += d2 * L2;
      accB[p] += nv * vlg - lZ;
    }
  }

  // per-lane: sum pairs; cross-quad via shuffle; cross-wave via LDS atomics
  float2v accp0 = accA[0] + accB[0];
  float2v accp1 = accA[1] + accB[1];
  float local = (accp0.x + accp0.y) + (accp1.x + accp1.y);
  local += __shfl_xor(local, 16);
  local += __shfl_xor(local, 32);
  if (quad == 0) atomicAdd(&redbuf[mrow], local);
  __syncthreads();
  if (tid < SPB) out[s0 + tid] = redbuf[tid] * (-LN2 / 1024.0f);
}

extern "C" void kernel_launch(void* const* d_in, const int* in_sizes, int n_in,
                              void* d_out, int out_size, void* d_ws, size_t ws_size,
                              hipStream_t stream){
  const float* w    = (const float*)d_in[0];
  const float* data = (const float*)d_in[1];
  const float* W1r  = (const float*)d_in[2];
  const float* b1r  = (const float*)d_in[3];
  const float* W2r  = (const float*)d_in[4];
  const float* b2r  = (const float*)d_in[5];
  const float* W3r  = (const float*)d_in[6];
  const float* b3r  = (const float*)d_in[7];
  const float* W1v  = (const float*)d_in[8];
  const float* b1v  = (const float*)d_in[9];
  const float* W2v  = (const float*)d_in[10];
  const float* b2v  = (const float*)d_in[11];
  const float* W3v  = (const float*)d_in[12];
  const float* b3v  = (const float*)d_in[13];
  unsigned short* pk = (unsigned short*)d_ws;   // 256KB W3 frags + 64KB W2 frags
  float* out = (float*)d_out;

  hipLaunchKernelGGL(pack_weights, dim3(80), dim3(256), 0, stream, W3r, W3v, W2r, W2v, pk);
  hipLaunchKernelGGL(cmp_fused, dim3(NS / SPB), dim3(256), 0, stream,
                     w, data, W1r, b1r, b2r, b3r,
                     W1v, b1v, b2v, b3v, pk, out);
}

// Round 6
// 462.181 us; speedup vs baseline: 1.0240x; 1.0240x over previous
//
#include <hip/hip_runtime.h>
#include <stdint.h>

#define XD 1024
#define NS 65536
#define SPB 16
#define N1 256
#define N2 64

#if __has_builtin(__builtin_amdgcn_exp2f)
#define EXP2F(x) __builtin_amdgcn_exp2f(x)
#else
#define EXP2F(x) exp2f(x)
#endif
#if __has_builtin(__builtin_amdgcn_logf)
#define LOG2F(x) __builtin_amdgcn_logf(x)
#else
#define LOG2F(x) log2f(x)
#endif
#if __has_builtin(__builtin_amdgcn_rcpf)
#define RCPF(x) __builtin_amdgcn_rcpf(x)
#else
#define RCPF(x) (1.0f/(x))
#endif

typedef __attribute__((ext_vector_type(8))) short short8;
typedef __attribute__((ext_vector_type(4))) float float4v;
typedef __attribute__((ext_vector_type(2))) float float2v;

#define LOG2E 1.4426950408889634f
#define LN2   0.6931471805599453f
#define NL2LN2 0.5287663729448977f

// pk layout (shorts):
//   [0 .. 131071]        W3 frags (2 mats x 64 cc x 2 kh x 64 lanes x 8)
//   [131072 .. 163839]   W2 B-frags (2 mats x 4 cw x 8 ks x 64 lanes x 8)
//   [163840 .. 180223]   W1pad A-frags (32 uc x 64 lanes x 8), K=32 zero-padded
#define PK2_OFF 131072
#define PK1_OFF 163840

static __device__ __forceinline__ float tanh_fast(float x){
  float e = EXP2F(x * 2.8853900817779268f);   // e^(2x)
  return (e - 1.0f) * RCPF(e + 1.0f);
}
static __device__ __forceinline__ unsigned short f2bf(float x){
  union { float f; uint32_t u; } c; c.f = x;
  uint32_t u = c.u;
  return (unsigned short)((u + 0x7FFFu + ((u >> 16) & 1u)) >> 16);
}
static __device__ __forceinline__ float2v exp2p(float2v e){
  float2v r; r.x = EXP2F(e.x); r.y = EXP2F(e.y); return r;
}
static __device__ __forceinline__ float2v v2log2(float2v a){
  float2v r; r.x = LOG2F(a.x); r.y = LOG2F(a.y); return r;
}
// softplus(y)/ln2 = log2(1 + 2^(y*LOG2E)).
// Valid without max-stabilization: |y| <= ~8.3 structurally (W3/b3 bounds).
static __device__ __forceinline__ float2v spb2u(float2v y){
  float2v a = y * LOG2E;
  float2v e; e.x = EXP2F(a.x); e.y = EXP2F(a.y);
  return v2log2(1.0f + e);
}

// log2(j!) for j=0..19 (runtime table only needs 0..9 for data!)
#define G2TAB_INIT {0.0f,0.0f,1.0f,2.5849625007f,4.5849625007f,6.9068905956f, \
  9.4918530963f,12.2992080189f,15.2992080189f,18.4691332114f,21.7910613063f, \
  25.2504929251f,28.8354554258f,32.5358951439f,36.3432500660f,40.2501406616f, \
  44.2501406616f,48.3376035030f,52.5075285040f,56.7554560173f}

// Pack W3 [64][1024], W2 [256][64], W1pad [32][512] (fp32) into bf16 MFMA frags.
__global__ void pack_weights(const float* __restrict__ W3r, const float* __restrict__ W3v,
                             const float* __restrict__ W2r, const float* __restrict__ W2v,
                             const float* __restrict__ W1r, const float* __restrict__ W1v,
                             unsigned short* __restrict__ pk){
  int tid = blockIdx.x * 256 + threadIdx.x;   // 0..22527
  unsigned short t[8];
  if (tid < 16384){
    int mat  = tid >> 13;
    int cc   = (tid >> 7) & 63;
    int kh   = (tid >> 6) & 1;
    int l    = tid & 63;
    int col  = cc * 16 + (l & 15);
    const float* W3 = mat ? W3v : W3r;
    int kbase = kh * 32 + (l >> 4) * 8;
    #pragma unroll
    for (int j = 0; j < 8; ++j) t[j] = f2bf(W3[(size_t)(kbase + j) * XD + col]);
    uint4 val;
    val.x = (uint32_t)t[0] | ((uint32_t)t[1] << 16);
    val.y = (uint32_t)t[2] | ((uint32_t)t[3] << 16);
    val.z = (uint32_t)t[4] | ((uint32_t)t[5] << 16);
    val.w = (uint32_t)t[6] | ((uint32_t)t[7] << 16);
    *(uint4*)(pk + (size_t)tid * 8) = val;
  } else if (tid < 20480){
    int t2 = tid - 16384;                     // 0..4095
    int mat = t2 >> 11;
    int cw  = (t2 >> 9) & 3;
    int ks  = (t2 >> 6) & 7;
    int l   = t2 & 63;
    const float* W2 = mat ? W2v : W2r;
    int kbase = ks * 32 + (l >> 4) * 8;
    int col = cw * 16 + (l & 15);
    #pragma unroll
    for (int j = 0; j < 8; ++j) t[j] = f2bf(W2[(size_t)(kbase + j) * N2 + col]);
    uint4 val;
    val.x = (uint32_t)t[0] | ((uint32_t)t[1] << 16);
    val.y = (uint32_t)t[2] | ((uint32_t)t[3] << 16);
    val.z = (uint32_t)t[4] | ((uint32_t)t[5] << 16);
    val.w = (uint32_t)t[6] | ((uint32_t)t[7] << 16);
    *(uint4*)(pk + (size_t)(PK2_OFF) + (size_t)t2 * 8) = val;
  } else {
    // W1pad A-frags: D[unit][sample] = W1pad[32 feats][512 units]^T . w
    // uc 0..15 = rate units 0..255; uc 16..31 = v units 0..255.
    // feature space = w's 32 columns; rate MLP input k: cols {0..7}->W1r rows
    // 0..7, cols {16..23}->rows 8..15; v: cols {8..15}->W1v rows 0..7,
    // cols {24..31}->rows 8..15; all other (feat,unit) pairs are ZERO.
    int t3 = tid - 20480;                     // 0..2047
    int uc = t3 >> 6;                         // 0..31
    int l  = t3 & 63;
    int mat = uc >> 4;
    int u   = (uc & 15) * 16 + (l & 15);      // unit within mat, 0..255
    int q   = l >> 4;
    const float* W1 = mat ? W1v : W1r;
    #pragma unroll
    for (int j = 0; j < 8; ++j){
      int f = q * 8 + j;                      // feature (w column) 0..31
      float val = 0.0f;
      if (mat == 0){
        if (f < 8)                    val = W1[f * N1 + u];
        else if (f >= 16 && f < 24)   val = W1[(f - 8) * N1 + u];
      } else {
        if (f >= 8 && f < 16)         val = W1[(f - 8) * N1 + u];
        else if (f >= 24)             val = W1[(f - 16) * N1 + u];
      }
      t[j] = f2bf(val);
    }
    uint4 val;
    val.x = (uint32_t)t[0] | ((uint32_t)t[1] << 16);
    val.y = (uint32_t)t[2] | ((uint32_t)t[3] << 16);
    val.z = (uint32_t)t[4] | ((uint32_t)t[5] << 16);
    val.w = (uint32_t)t[6] | ((uint32_t)t[7] << 16);
    *(uint4*)(pk + (size_t)(PK1_OFF) + (size_t)t3 * 8) = val;
  }
}

// launch_bounds(256,4): VGPR cap 128. (256,8) forced 32 VGPRs -> scratch spills
// (WRITE_SIZE 65MB) and 43% regression. Occupancy pinned at 4 waves/SIMD.
// NOTE (r3): inline-asm v_pk_* helpers -> NaN; don't reintroduce.
// NOTE (r5): exp2poly for large primes LOST 3% vs direct v_exp — trans pipe is
// NOT the wall; regular VALU issue count is. Keep all 8 q-exps scalar.
__global__ __launch_bounds__(256, 4) void cmp_fused(
    const float* __restrict__ w,   const float* __restrict__ data,
    const float* __restrict__ b1r, const float* __restrict__ b2r,
    const float* __restrict__ b3r, const float* __restrict__ b1v,
    const float* __restrict__ b2v, const float* __restrict__ b3v,
    const unsigned short* __restrict__ pk,
    float* __restrict__ out)
{
  __shared__ __align__(16) unsigned short h1lds[2][SPB * 264];  // stride 264 (pad +8)
  __shared__ __align__(16) unsigned short h2lds[2][SPB * 72];   // stride 72 (pad +8)
  __shared__ float lgf2[20];
  __shared__ float redbuf[SPB];

  const float G2tab[20] = G2TAB_INIT;

  int tid = threadIdx.x;
  int s0  = blockIdx.x * SPB;
  int lane = tid & 63;
  int wv_id = tid >> 6;
  int quad = lane >> 4;
  int mrow = lane & 15;

  if (tid < 20)  lgf2[tid] = G2tab[tid];
  if (tid < SPB) redbuf[tid] = 0.0f;
  // (no barrier needed: lgf2/redbuf first used after the phase-1 barriers)

  // ---------------- phase 1a: layer 1 via MFMA ----------------
  // B-frag: w row (sample=mrow, feats quad*8..+8) straight from global, bf16.
  short8 wb;
  {
    const float* wrow = w + (size_t)(s0 + mrow) * 32 + quad * 8;
    float4v w0 = *(const float4v*)(wrow);
    float4v w1 = *(const float4v*)(wrow + 4);
    uint4 ub;
    ub.x = (uint32_t)f2bf(w0.x) | ((uint32_t)f2bf(w0.y) << 16);
    ub.y = (uint32_t)f2bf(w0.z) | ((uint32_t)f2bf(w0.w) << 16);
    ub.z = (uint32_t)f2bf(w1.x) | ((uint32_t)f2bf(w1.y) << 16);
    ub.w = (uint32_t)f2bf(w1.z) | ((uint32_t)f2bf(w1.w) << 16);
    union { uint4 u; short8 s; } cvt; cvt.u = ub; wb = cvt.s;
  }
  // 8 unit-chunks per wave: wv0-1 -> rate units, wv2-3 -> v units.
  {
    const short8* W1p = (const short8*)(pk + PK1_OFF);
    const float* b1sel = (wv_id < 2) ? b1r : b1v;
    #pragma unroll
    for (int i = 0; i < 8; ++i){
      int uc = wv_id * 8 + i;
      short8 af = W1p[(size_t)uc * 64 + lane];
      float4v acc = {0,0,0,0};
      acc = __builtin_amdgcn_mfma_f32_16x16x32_bf16(af, wb, acc, 0, 0, 0);
      float4v bb = *(const float4v*)(b1sel + ((uc & 15) * 16 + quad * 4));
      float4v hp = acc + bb;
      uint2 val;
      val.x = (uint32_t)f2bf(tanh_fast(hp.x)) | ((uint32_t)f2bf(tanh_fast(hp.y)) << 16);
      val.y = (uint32_t)f2bf(tanh_fast(hp.z)) | ((uint32_t)f2bf(tanh_fast(hp.w)) << 16);
      int mat = uc >> 4;
      // D: col(lane&15)=sample, rows = units (uc&15)*16 + quad*4 + r (consecutive)
      *(uint2*)&h1lds[mat][mrow * 264 + (uc & 15) * 16 + quad * 4] = val;
    }
  }
  __syncthreads();

  // ---------------- phase 1b: layer 2 (MFMA), both mats ----------------
  const short8* B2p = (const short8*)(pk + PK2_OFF);
  #pragma unroll
  for (int mat = 0; mat < 2; ++mat){
    const float* b2 = mat ? b2v : b2r;
    int cw = wv_id;
    float4v acc = {0,0,0,0};
    #pragma unroll
    for (int ks = 0; ks < 8; ++ks){
      short8 bfr = B2p[(size_t)((mat * 4 + cw) * 8 + ks) * 64 + lane];
      short8 a = *(const short8*)&h1lds[mat][mrow * 264 + ks * 32 + quad * 8];
      acc = __builtin_amdgcn_mfma_f32_16x16x32_bf16(a, bfr, acc, 0, 0, 0);
    }
    float b2n = b2[cw * 16 + mrow];
    #pragma unroll
    for (int r = 0; r < 4; ++r){
      int sample = quad * 4 + r;
      h2lds[mat][sample * 72 + cw * 16 + mrow] = f2bf(tanh_fast(acc[r] + b2n));
    }
  }
  __syncthreads();

  // ---------------- phase 2: layer3 MFMA (A=W3, B=h2) + packed elementwise ----
  // B-frag: h2[k=unit][n=sample]; lane holds n=mrow (one sample), k=quad*8+j
  short8 bh[2][2];   // [mat][k-half]
  #pragma unroll
  for (int mat = 0; mat < 2; ++mat)
    #pragma unroll
    for (int kh = 0; kh < 2; ++kh)
      bh[mat][kh] = *(const short8*)&h2lds[mat][mrow * 72 + kh * 32 + quad * 8];

  // split accumulators (plain vector ops): shorter dependency chains
  float2v accA[2] = {{0, 0}, {0, 0}};
  float2v accB[2] = {{0, 0}, {0, 0}};
  const short8* Bp = (const short8*)pk;
  const float* drow = data + (size_t)(s0 + mrow) * XD;

  // prefetch pipeline registers for iteration 0
  int cc0 = wv_id * 16;
  short8 ar0 = Bp[(size_t)(cc0 * 2 + 0) * 64 + lane];
  short8 ar1 = Bp[(size_t)(cc0 * 2 + 1) * 64 + lane];
  short8 av0 = Bp[(size_t)((64 + cc0) * 2 + 0) * 64 + lane];
  short8 av1 = Bp[(size_t)((64 + cc0) * 2 + 1) * 64 + lane];
  int colq0 = cc0 * 16 + quad * 4;
  float4v b3rv = *(const float4v*)(b3r + colq0);
  float4v b3vv = *(const float4v*)(b3v + colq0);
  float4v dv   = *(const float4v*)(drow + colq0);

  for (int it = 0; it < 16; ++it){
    // stash current, prefetch next (uniform branch)
    short8 car0 = ar0, car1 = ar1, cav0 = av0, cav1 = av1;
    float4v cb3r = b3rv, cb3v = b3vv, cdv = dv;
    if (it < 15){
      int cc = wv_id * 16 + it + 1;
      ar0 = Bp[(size_t)(cc * 2 + 0) * 64 + lane];
      ar1 = Bp[(size_t)(cc * 2 + 1) * 64 + lane];
      av0 = Bp[(size_t)((64 + cc) * 2 + 0) * 64 + lane];
      av1 = Bp[(size_t)((64 + cc) * 2 + 1) * 64 + lane];
      int colq = cc * 16 + quad * 4;
      b3rv = *(const float4v*)(b3r + colq);
      b3vv = *(const float4v*)(b3v + colq);
      dv   = *(const float4v*)(drow + colq);
    }
    float4v cr = {0,0,0,0}, cv = {0,0,0,0};
    cr = __builtin_amdgcn_mfma_f32_16x16x32_bf16(car0, bh[0][0], cr, 0, 0, 0);
    cr = __builtin_amdgcn_mfma_f32_16x16x32_bf16(car1, bh[0][1], cr, 0, 0, 0);
    cv = __builtin_amdgcn_mfma_f32_16x16x32_bf16(cav0, bh[1][0], cv, 0, 0, 0);
    cv = __builtin_amdgcn_mfma_f32_16x16x32_bf16(cav1, bh[1][1], cv, 0, 0, 0);
    // vector-typed bias adds
    float4v yr4 = cr + cb3r;
    float4v yv4 = cv + cb3v;
    // process the 4 columns as 2 packed pairs
    #pragma unroll
    for (int p = 0; p < 2; ++p){
      float2v yr = {yr4[2*p], yr4[2*p+1]};
      float2v yv = {yv4[2*p], yv4[2*p+1]};
      float2v d2 = {cdv[2*p], cdv[2*p+1]};
      // rate side: spr = softplus(yr)/ln2; L2 = log2(rate); rate via rcp
      float2v spr = spb2u(yr);
      float2v L2  = NL2LN2 - v2log2(spr);
      float2v rate;
      rate.x = RCPF(spr.x) * LOG2E;
      rate.y = RCPF(spr.y) * LOG2E;
      // v side: nv = -v = -softplus(yv)
      float2v nv = spb2u(yv) * (-LN2);
      // rq_j = rate * j^-v from prime powers q_p = 2^(nv*log2 p).
      float2v q2  = exp2p(nv);
      float2v q3  = exp2p(nv * 1.58496250f);
      float2v q5  = exp2p(nv * 2.32192809f);
      float2v q7  = exp2p(nv * 2.80735492f);
      float2v q11 = exp2p(nv * 3.45943162f);
      float2v q13 = exp2p(nv * 3.70043972f);
      float2v q17 = exp2p(nv * 4.08746284f);
      float2v q19 = exp2p(nv * 4.24792751f);
      float2v rq2  = rate * q2,  rq3  = rate * q3,  rq5 = rate * q5,  rq7 = rate * q7;
      float2v rq11 = rate * q11, rq13 = rate * q13, rq17 = rate * q17, rq19 = rate * q19;
      float2v rq4  = rq2 * q2,  rq6  = rq2 * q3,  rq8 = rq4 * q2,  rq9 = rq3 * q3;
      float2v rq10 = rq5 * q2;
      float2v rq12 = rq4 * q3,  rq14 = rq2 * q7,  rq15 = rq3 * q5;
      float2v rq16 = rq8 * q2,  rq18 = rq9 * q2;
      // Z = 1 + rate*(1 + rq2*(1 + rq3*(... (1 + rq19) ...))): 19 packed FMAs
      float2v zi = 1.0f + rq19;
      zi = rq18 * zi + 1.0f;
      zi = rq17 * zi + 1.0f;
      zi = rq16 * zi + 1.0f;
      zi = rq15 * zi + 1.0f;
      zi = rq14 * zi + 1.0f;
      zi = rq13 * zi + 1.0f;
      zi = rq12 * zi + 1.0f;
      zi = rq11 * zi + 1.0f;
      zi = rq10 * zi + 1.0f;
      zi = rq9  * zi + 1.0f;
      zi = rq8  * zi + 1.0f;
      zi = rq7  * zi + 1.0f;
      zi = rq6  * zi + 1.0f;
      zi = rq5  * zi + 1.0f;
      zi = rq4  * zi + 1.0f;
      zi = rq3  * zi + 1.0f;
      zi = rq2  * zi + 1.0f;
      float2v Z = rate * zi + 1.0f;
      float2v lZ = v2log2(Z);
      float2v vlg; vlg.x = lgf2[(int)d2.x]; vlg.y = lgf2[(int)d2.y];
      // log2-scaled logpmf: d*L2 + nv*log2(d!) - log2Z (split across 2 accs)
      accA[p] += d2 * L2;
      accB[p] += nv * vlg - lZ;
    }
  }

  // per-lane: sum pairs; cross-quad via shuffle; cross-wave via LDS atomics
  float2v accp0 = accA[0] + accB[0];
  float2v accp1 = accA[1] + accB[1];
  float local = (accp0.x + accp0.y) + (accp1.x + accp1.y);
  local += __shfl_xor(local, 16);
  local += __shfl_xor(local, 32);
  if (quad == 0) atomicAdd(&redbuf[mrow], local);
  __syncthreads();
  if (tid < SPB) out[s0 + tid] = redbuf[tid] * (-LN2 / 1024.0f);
}

extern "C" void kernel_launch(void* const* d_in, const int* in_sizes, int n_in,
                              void* d_out, int out_size, void* d_ws, size_t ws_size,
                              hipStream_t stream){
  const float* w    = (const float*)d_in[0];
  const float* data = (const float*)d_in[1];
  const float* W1r  = (const float*)d_in[2];
  const float* b1r  = (const float*)d_in[3];
  const float* W2r  = (const float*)d_in[4];
  const float* b2r  = (const float*)d_in[5];
  const float* W3r  = (const float*)d_in[6];
  const float* b3r  = (const float*)d_in[7];
  const float* W1v  = (const float*)d_in[8];
  const float* b1v  = (const float*)d_in[9];
  const float* W2v  = (const float*)d_in[10];
  const float* b2v  = (const float*)d_in[11];
  const float* W3v  = (const float*)d_in[12];
  const float* b3v  = (const float*)d_in[13];
  unsigned short* pk = (unsigned short*)d_ws;   // 256KB W3 + 64KB W2 + 32KB W1 frags
  float* out = (float*)d_out;

  hipLaunchKernelGGL(pack_weights, dim3(88), dim3(256), 0, stream,
                     W3r, W3v, W2r, W2v, W1r, W1v, pk);
  hipLaunchKernelGGL(cmp_fused, dim3(NS / SPB), dim3(256), 0, stream,
                     w, data, b1r, b2r, b3r,
                     b1v, b2v, b3v, pk, out);
}